// Round 5
// baseline (292.616 us; speedup 1.0000x reference)
//
#include <hip/hip_runtime.h>
#include <hip/hip_bf16.h>

#define BB 16
#define SS 4096
#define CC 512
#define NTOK (BB * SS)
#define LOSS_BLOCKS 2048
#define WAVES_TOTAL (LOSS_BLOCKS * 4)       // 8192
#define WPB (WAVES_TOTAL / BB)              // 512 waves per batch

// ws layout:
//   acc[32]   float : (sum,cnt) per batch          offset 0
//   cursors[16] int : per-batch compaction cursor  offset 128
//   idxbuf[BB*SS] int: per-batch compacted lists   offset 256

// Phase A: compact active token indices into per-batch lists.
// 256 blocks x 256 threads; block = 256 consecutive tokens of one batch.
__global__ __launch_bounds__(256) void compact_kernel(
    const int* __restrict__ mask,
    int*       __restrict__ idxbuf,
    int*       __restrict__ cursors,
    float*     __restrict__ acc) {
    const int t     = blockIdx.x * 256 + threadIdx.x;
    const int batch = blockIdx.x / 16;          // 16 blocks per batch
    const int lane  = threadIdx.x & 63;
    const int wave  = threadIdx.x >> 6;

    const bool active = (mask[t] == 1);
    unsigned long long ball = __ballot(active);
    const int prefix = __popcll(ball & ((1ull << lane) - 1ull));
    const int wcount = __popcll(ball);

    __shared__ int wbase[4];
    __shared__ int blockbase;
    if (lane == 0) wbase[wave] = wcount;
    __syncthreads();
    if (threadIdx.x == 0) {
        int total = wbase[0] + wbase[1] + wbase[2] + wbase[3];
        blockbase = atomicAdd(&cursors[batch], total);
        atomicAdd(&acc[2 * batch + 1], (float)total);
        int s = 0;
        for (int i = 0; i < 4; ++i) { int c = wbase[i]; wbase[i] = s; s += c; }
    }
    __syncthreads();
    if (active)
        idxbuf[batch * SS + blockbase + wbase[wave] + prefix] = t;
}

// Phase B: branchless pipelined loss over compacted lists.
// wave wid -> batch = wid & 15, slot w2 = wid >> 4 (0..511), stride 512.
// 2-stage register pipeline: next token's loads in flight while computing
// current. dot deferred to one end reduction; se butterfly in-loop.
__global__ __launch_bounds__(256, 8) void loss_kernel(
    const float* __restrict__ logits,
    const float* __restrict__ target,
    const int*   __restrict__ idxbuf,
    const int*   __restrict__ cursors,
    float*       __restrict__ acc) {
    const int wave  = threadIdx.x >> 6;
    const int lane  = threadIdx.x & 63;
    const int wid   = blockIdx.x * 4 + wave;
    const int batch = wid & (BB - 1);
    const int w2    = wid >> 4;
    const int cnt   = cursors[batch];
    const int* list = idxbuf + batch * SS;

    float dotAcc = 0.0f;
    float logAcc = 0.0f;

    int k = w2;
    bool have = (k < cnt);
    float4 x0, x1, t0, t1;
    if (have) {
        const int tok = list[k];
        const float4* xp = (const float4*)(logits + (size_t)tok * CC);
        const float4* tp = (const float4*)(target + (size_t)tok * CC);
        x0 = xp[lane]; x1 = xp[lane + 64];
        t0 = tp[lane]; t1 = tp[lane + 64];
    }
    while (have) {
        const int kn = k + WPB;
        const bool haveN = (kn < cnt);
        float4 nx0, nx1, nt0, nt1;
        if (haveN) {  // prefetch next token before consuming current
            const int tokN = list[kn];
            const float4* xp = (const float4*)(logits + (size_t)tokN * CC);
            const float4* tp = (const float4*)(target + (size_t)tokN * CC);
            nx0 = xp[lane]; nx1 = xp[lane + 64];
            nt0 = tp[lane]; nt1 = tp[lane + 64];
        }
        float se = __expf(x0.x) + __expf(x0.y) + __expf(x0.z) + __expf(x0.w)
                 + __expf(x1.x) + __expf(x1.y) + __expf(x1.z) + __expf(x1.w);
        dotAcc += t0.x * x0.x + t0.y * x0.y + t0.z * x0.z + t0.w * x0.w
                + t1.x * x1.x + t1.y * x1.y + t1.z * x1.z + t1.w * x1.w;
        #pragma unroll
        for (int off = 32; off >= 1; off >>= 1)
            se += __shfl_xor(se, off, 64);
        logAcc += __logf(se);
        x0 = nx0; x1 = nx1; t0 = nt0; t1 = nt1;
        k = kn; have = haveN;
    }

    #pragma unroll
    for (int off = 32; off >= 1; off >>= 1)
        dotAcc += __shfl_xor(dotAcc, off, 64);

    if (lane == 0) {
        float contrib = logAcc - dotAcc;
        if (contrib != 0.0f) atomicAdd(&acc[2 * batch], contrib);
    }
}

// One wave reads the 16 (sum,cnt) pairs and produces the scalar.
__global__ __launch_bounds__(64) void finalize_kernel(
    const float* __restrict__ acc,
    float*       __restrict__ out) {
    const int lane = threadIdx.x;
    float pb = 0.0f, has = 0.0f;
    if (lane < BB) {
        float s = acc[2 * lane];
        float c = acc[2 * lane + 1];
        if (c > 0.0f) { pb = s / c; has = 1.0f; }
    }
    #pragma unroll
    for (int off = 32; off >= 1; off >>= 1) {
        pb  += __shfl_xor(pb, off, 64);
        has += __shfl_xor(has, off, 64);
    }
    if (lane == 0) out[0] = pb / fmaxf(has, 1.0f);
}

extern "C" void kernel_launch(void* const* d_in, const int* in_sizes, int n_in,
                              void* d_out, int out_size, void* d_ws, size_t ws_size,
                              hipStream_t stream) {
    const float* logits = (const float*)d_in[0];
    const float* target = (const float*)d_in[1];
    const int*   mask   = (const int*)d_in[2];
    float* out     = (float*)d_out;
    float* acc     = (float*)d_ws;                       // 32 floats
    int*   cursors = (int*)((char*)d_ws + 128);          // 16 ints
    int*   idxbuf  = (int*)((char*)d_ws + 256);          // BB*SS ints

    hipMemsetAsync(d_ws, 0, 192, stream);
    compact_kernel<<<NTOK / 256, 256, 0, stream>>>(mask, idxbuf, cursors, acc);
    loss_kernel<<<LOSS_BLOCKS, 256, 0, stream>>>(logits, target, idxbuf, cursors, acc);
    finalize_kernel<<<1, 64, 0, stream>>>(acc, out);
}

// Round 6
// 255.778 us; speedup vs baseline: 1.1440x; 1.1440x over previous
//
#include <hip/hip_runtime.h>
#include <hip/hip_bf16.h>

#define BB 16
#define SS 4096
#define CC 512
#define NTOK (BB * SS)
#define LOSS_BLOCKS 2048
#define BLOCKS_PER_BATCH (LOSS_BLOCKS / BB)   // 128
#define WPB (BLOCKS_PER_BATCH * 4)            // 512 waves per batch

// ws layout:
//   cursors[16] int  @ 0      per-batch active count (atomic cursor)
//   idxbuf[NTOK] int @ 128    per-batch compacted token lists
//   partial[2048] f  @ 128+NTOK*4   per-block loss partials (plain stores)

// Phase A: compact active token indices into per-batch lists.
__global__ __launch_bounds__(256) void compact_kernel(
    const int* __restrict__ mask,
    int*       __restrict__ idxbuf,
    int*       __restrict__ cursors) {
    const int t     = blockIdx.x * 256 + threadIdx.x;
    const int batch = blockIdx.x / 16;          // 16 blocks per batch
    const int lane  = threadIdx.x & 63;
    const int wave  = threadIdx.x >> 6;

    const bool active = (mask[t] == 1);
    unsigned long long ball = __ballot(active);
    const int prefix = __popcll(ball & ((1ull << lane) - 1ull));
    const int wcount = __popcll(ball);

    __shared__ int wbase[4];
    __shared__ int blockbase;
    if (lane == 0) wbase[wave] = wcount;
    __syncthreads();
    if (threadIdx.x == 0) {
        int total = wbase[0] + wbase[1] + wbase[2] + wbase[3];
        blockbase = atomicAdd(&cursors[batch], total);
        int s = 0;
        for (int i = 0; i < 4; ++i) { int c = wbase[i]; wbase[i] = s; s += c; }
    }
    __syncthreads();
    if (active)
        idxbuf[batch * SS + blockbase + wbase[wave] + prefix] = t;
}

// Phase B: identical K-loop to round 5 (depth-1 register pipeline), but
// all 4 waves of a block serve ONE batch and the block's partial goes out
// via a plain store — ZERO device atomics in this kernel.
__global__ __launch_bounds__(256, 8) void loss_kernel(
    const float* __restrict__ logits,
    const float* __restrict__ target,
    const int*   __restrict__ idxbuf,
    const int*   __restrict__ cursors,
    float*       __restrict__ partial) {
    const int wave  = threadIdx.x >> 6;
    const int lane  = threadIdx.x & 63;
    const int batch = blockIdx.x >> 7;                       // 128 blocks/batch
    const int wib   = (blockIdx.x & (BLOCKS_PER_BATCH - 1)) * 4 + wave;  // 0..511
    const int cnt   = cursors[batch];
    const int* list = idxbuf + batch * SS;

    float dotAcc = 0.0f;
    float logAcc = 0.0f;

    int k = wib;
    bool have = (k < cnt);
    float4 x0, x1, t0, t1;
    if (have) {
        const int tok = list[k];
        const float4* xp = (const float4*)(logits + (size_t)tok * CC);
        const float4* tp = (const float4*)(target + (size_t)tok * CC);
        x0 = xp[lane]; x1 = xp[lane + 64];
        t0 = tp[lane]; t1 = tp[lane + 64];
    }
    while (have) {
        const int kn = k + WPB;
        const bool haveN = (kn < cnt);
        float4 nx0, nx1, nt0, nt1;
        if (haveN) {  // prefetch next token before consuming current
            const int tokN = list[kn];
            const float4* xp = (const float4*)(logits + (size_t)tokN * CC);
            const float4* tp = (const float4*)(target + (size_t)tokN * CC);
            nx0 = xp[lane]; nx1 = xp[lane + 64];
            nt0 = tp[lane]; nt1 = tp[lane + 64];
        }
        float se = __expf(x0.x) + __expf(x0.y) + __expf(x0.z) + __expf(x0.w)
                 + __expf(x1.x) + __expf(x1.y) + __expf(x1.z) + __expf(x1.w);
        dotAcc += t0.x * x0.x + t0.y * x0.y + t0.z * x0.z + t0.w * x0.w
                + t1.x * x1.x + t1.y * x1.y + t1.z * x1.z + t1.w * x1.w;
        #pragma unroll
        for (int off = 32; off >= 1; off >>= 1)
            se += __shfl_xor(se, off, 64);
        logAcc += __logf(se);
        x0 = nx0; x1 = nx1; t0 = nt0; t1 = nt1;
        k = kn; have = haveN;
    }

    #pragma unroll
    for (int off = 32; off >= 1; off >>= 1)
        dotAcc += __shfl_xor(dotAcc, off, 64);

    __shared__ float ls[4];
    if (lane == 0) ls[wave] = logAcc - dotAcc;
    __syncthreads();
    if (threadIdx.x == 0)
        partial[blockIdx.x] = ls[0] + ls[1] + ls[2] + ls[3];   // plain store
}

// One block, 16 waves: wave w reduces batch w's 128 partials, divides by
// its count from cursors, then thread 0 averages the non-empty batches.
__global__ __launch_bounds__(1024) void finalize_kernel(
    const float* __restrict__ partial,
    const int*   __restrict__ cursors,
    float*       __restrict__ out) {
    const int wave = threadIdx.x >> 6;   // 0..15 = batch
    const int lane = threadIdx.x & 63;

    float s = partial[wave * BLOCKS_PER_BATCH + lane]
            + partial[wave * BLOCKS_PER_BATCH + 64 + lane];
    #pragma unroll
    for (int off = 32; off >= 1; off >>= 1)
        s += __shfl_xor(s, off, 64);

    __shared__ float pb[BB], has[BB];
    if (lane == 0) {
        float c = (float)cursors[wave];
        pb[wave]  = (c > 0.0f) ? s / c : 0.0f;
        has[wave] = (c > 0.0f) ? 1.0f : 0.0f;
    }
    __syncthreads();
    if (threadIdx.x == 0) {
        float acc = 0.0f, nb = 0.0f;
        for (int b = 0; b < BB; ++b) { acc += pb[b]; nb += has[b]; }
        out[0] = acc / fmaxf(nb, 1.0f);
    }
}

extern "C" void kernel_launch(void* const* d_in, const int* in_sizes, int n_in,
                              void* d_out, int out_size, void* d_ws, size_t ws_size,
                              hipStream_t stream) {
    const float* logits = (const float*)d_in[0];
    const float* target = (const float*)d_in[1];
    const int*   mask   = (const int*)d_in[2];
    float* out     = (float*)d_out;
    int*   cursors = (int*)d_ws;                              // 16 ints
    int*   idxbuf  = (int*)((char*)d_ws + 128);               // NTOK ints
    float* partial = (float*)((char*)d_ws + 128 + NTOK * 4);  // 2048 floats

    hipMemsetAsync(cursors, 0, 64, stream);
    compact_kernel<<<NTOK / 256, 256, 0, stream>>>(mask, idxbuf, cursors);
    loss_kernel<<<LOSS_BLOCKS, 256, 0, stream>>>(logits, target, idxbuf, cursors, partial);
    finalize_kernel<<<1, 1024, 0, stream>>>(partial, cursors, out);
}